// Round 8
// baseline (1103.320 us; speedup 1.0000x reference)
//
#include <hip/hip_runtime.h>
#include <math.h>
#include <float.h>

#define INPUT_DIM 1024
#define HIDDEN 128
#define KSEL 10

// scores kernel geometry: 4 consumer waves + 1 producer wave
#define BM 64
#define BK 64
#define KT (INPUT_DIM / BK)   // 16
#define CW 4                  // consumer waves
#define STH 320               // 5 waves
#define NSEL1 32              // stage-1 chunks per bag

typedef short short8 __attribute__((ext_vector_type(8)));
typedef float f32x4 __attribute__((ext_vector_type(4)));

static __device__ __forceinline__ unsigned short f2bf(float f) {
    union { float f; unsigned u; } v; v.f = f;
    unsigned r = v.u + 0x7FFF + ((v.u >> 16) & 1);   // RNE
    return (unsigned short)(r >> 16);
}
static __device__ __forceinline__ float bf2f(unsigned short h) {
    union { unsigned u; float f; } v; v.u = ((unsigned)h) << 16;
    return v.f;
}
// split (a,b) -> packed hi word (truncation) + packed lo word (RNE of residual)
static __device__ __forceinline__ void split2(float a, float b, unsigned& hw, unsigned& lw) {
    unsigned ua = __float_as_uint(a) & 0xFFFF0000u;
    unsigned ub = __float_as_uint(b) & 0xFFFF0000u;
    float ra = a - __uint_as_float(ua);
    float rb = b - __uint_as_float(ub);
    asm("v_perm_b32 %0, %1, %2, %3" : "=v"(hw) : "v"(ub), "v"(ua), "s"(0x07060302));
    asm("v_cvt_pk_bf16_f32 %0, %1, %2" : "=v"(lw) : "v"(ra), "v"(rb));
}
static __device__ __forceinline__ float fast_tanh(float a) {
    float e = __expf(2.0f * a);
    return 1.0f - 2.0f / (e + 1.0f);
}
static __device__ __forceinline__ float fast_sigmoid(float a) {
    return 1.0f / (1.0f + __expf(-a));
}

// ---------------------------------------------------------------------------
// Repack W into MFMA B-fragment order, split into bf16 hi/lo (RNE both).
// pc = 2h + (0 Wv, 1 Wu). wp[kg][cg][lane][e]: k = kg*32+(lane>>4)*8+e,
// pc = cg*16+(lane&15). grid 512 x 64.
// ---------------------------------------------------------------------------
__global__ __launch_bounds__(64) void repack_kernel(
    const float* __restrict__ Wv, const float* __restrict__ Wu,
    unsigned short* __restrict__ wp_hi, unsigned short* __restrict__ wp_lo)
{
    int bid = blockIdx.x;           // kg*16 + cg
    int l = threadIdx.x;
    int pc = (bid & 15) * 16 + (l & 15);
    int h = pc >> 1;
    const float* src = (pc & 1) ? Wu : Wv;
    int kbase = (bid >> 4) * 32 + (l >> 4) * 8;
    size_t off = ((size_t)bid * 64 + l) * 8;
    #pragma unroll
    for (int e = 0; e < 8; ++e) {
        float w = src[(size_t)(kbase + e) * HIDDEN + h];
        unsigned short hi = f2bf(w);
        unsigned short lo = f2bf(w - bf2f(hi));
        wp_hi[off + e] = hi;
        wp_lo[off + e] = lo;
    }
}

// ---------------------------------------------------------------------------
// Kernel 1: fused scores via split-bf16 3-term MFMA, PRODUCER/CONSUMER waves.
// Producer (wave 4): stages raw fp32 x tiles via global_load_lds into a
//   3-buffer rotation, 2 tiles in flight, counted vmcnt(16) + 1 barrier/step.
//   Its vmcnt queue holds ONLY DMA -> counted waits work (no FIFO pollution).
// Consumers (waves 0-3): B-frag L2 loads on their own vmcnt queue (~200cy),
//   swizzled ds_read_b128 of x, in-register hi/lo split, 96 MFMA per step.
// Source-side XOR swizzle (chunk ^= row&7, involution) keeps reads
// conflict-free with a linear DMA destination (rule-21 pattern).
// ---------------------------------------------------------------------------
__global__ __launch_bounds__(STH) void scores_kernel(
    const float* __restrict__ x,
    const unsigned short* __restrict__ wp_hi, const unsigned short* __restrict__ wp_lo,
    const float* __restrict__ bv, const float* __restrict__ bu,
    const float* __restrict__ Ww, const float* __restrict__ bw,
    float* __restrict__ scores, float* __restrict__ atten, int N)
{
    __shared__ __align__(16) float buf[3][BM * BK];   // 48 KB (3 x 16 KB)
    __shared__ float partial[CW][BM];                 // 1 KB

    const int tid = threadIdx.x;
    const int l = tid & 63;
    const int w = tid >> 6;        // 0..3 consumers, 4 producer
    const int b = blockIdx.y;
    const int i0 = blockIdx.x * BM;
    const float* xb = x + (size_t)b * N * INPUT_DIM;

    f32x4 acc[4][4];
    #pragma unroll
    for (int m = 0; m < 4; ++m)
        #pragma unroll
        for (int n = 0; n < 4; ++n)
            acc[m][n] = (f32x4){0.f, 0.f, 0.f, 0.f};

    if (w == CW) {
        // ================= producer wave =================
        // load j covers rows [j*4, j*4+4) x 16 chunks; dest linear lane*16B.
        // LDS[row][c] holds global chunk (c ^ (row&7)); clamp tail rows.
        const float* gp[16];
        #pragma unroll
        for (int j = 0; j < 16; ++j) {
            int lr = j * 4 + (l >> 4);
            int gi = min(i0 + lr, N - 1);
            int csw = (l & 15) ^ (lr & 7);
            gp[j] = xb + (size_t)gi * INPUT_DIM + csw * 4;
        }
        // prologue: stage tiles 0 and 1
        #pragma unroll
        for (int t = 0; t < 2; ++t) {
            #pragma unroll
            for (int j = 0; j < 16; ++j) {
                __builtin_amdgcn_global_load_lds(
                    (const __attribute__((address_space(1))) void*)gp[j],
                    (__attribute__((address_space(3))) void*)&buf[t][j * 4 * BK],
                    16, 0, 0);
                gp[j] += BK;
            }
        }
        for (int kt = 0; kt < KT; ++kt) {
            // ensure tile kt landed; keep tile kt+1 in flight (counted wait)
            if (kt < KT - 1) asm volatile("s_waitcnt vmcnt(16)" ::: "memory");
            else             asm volatile("s_waitcnt vmcnt(0)"  ::: "memory");
            __builtin_amdgcn_s_barrier();
            if (kt + 2 < KT) {
                // overwrite buf[(kt+2)%3] == buf[(kt-1)%3]; consumers finished
                // reading tile kt-1 before this barrier -> safe.
                float* dst = &buf[(kt + 2) % 3][0];
                #pragma unroll
                for (int j = 0; j < 16; ++j) {
                    __builtin_amdgcn_global_load_lds(
                        (const __attribute__((address_space(1))) void*)gp[j],
                        (__attribute__((address_space(3))) void*)(dst + j * 4 * BK),
                        16, 0, 0);
                    gp[j] += BK;
                }
            }
        }
    } else {
        // ================= consumer waves =================
        for (int kt = 0; kt < KT; ++kt) {
            __builtin_amdgcn_s_barrier();
            const float* BUF = &buf[kt % 3][0];
            #pragma unroll
            for (int ks = 0; ks < 2; ++ks) {
                const int kg = kt * 2 + ks;
                short8 bh[4], bl[4];
                #pragma unroll
                for (int n = 0; n < 4; ++n) {
                    unsigned boff = (unsigned)(((kg * 16 + w * 4 + n) * 64 + l) * 8);
                    bh[n] = *(const short8*)(wp_hi + boff);
                    bl[n] = *(const short8*)(wp_lo + boff);
                }
                __builtin_amdgcn_s_setprio(1);
                #pragma unroll
                for (int m = 0; m < 4; ++m) {
                    int row = m * 16 + (l & 15);
                    int k4a = ks * 8 + (l >> 4) * 2;     // first 4-float chunk
                    int sw = l & 7;                      // row&7 == l&7 here
                    f32x4 c0 = *(const f32x4*)(&BUF[row * BK + ((k4a)     ^ sw) * 4]);
                    f32x4 c1 = *(const f32x4*)(&BUF[row * BK + ((k4a + 1) ^ sw) * 4]);
                    union { short8 s; uint4 u; } Ah, Al;
                    split2(c0[0], c0[1], Ah.u.x, Al.u.x);
                    split2(c0[2], c0[3], Ah.u.y, Al.u.y);
                    split2(c1[0], c1[1], Ah.u.z, Al.u.z);
                    split2(c1[2], c1[3], Ah.u.w, Al.u.w);
                    #pragma unroll
                    for (int n = 0; n < 4; ++n) {
                        acc[m][n] = __builtin_amdgcn_mfma_f32_16x16x32_bf16(Ah.s, bh[n], acc[m][n], 0, 0, 0);
                        acc[m][n] = __builtin_amdgcn_mfma_f32_16x16x32_bf16(Al.s, bh[n], acc[m][n], 0, 0, 0);
                        acc[m][n] = __builtin_amdgcn_mfma_f32_16x16x32_bf16(Ah.s, bl[n], acc[m][n], 0, 0, 0);
                    }
                }
                __builtin_amdgcn_s_setprio(0);
            }
        }
    }

    // ---- epilogue: gate, project, row-reduce (consumers only compute) ----
    if (w < CW) {
        float bvv[4], buu[4], www[4];
        #pragma unroll
        for (int n = 0; n < 4; ++n) {
            int h = (w * 64 + n * 16 + (l & 15)) >> 1;
            bvv[n] = bv[h]; buu[n] = bu[h]; www[n] = Ww[h];
        }
        const bool isV = ((l & 1) == 0);

        #pragma unroll
        for (int m = 0; m < 4; ++m) {
            float cs[4] = {0.f, 0.f, 0.f, 0.f};
            #pragma unroll
            for (int n = 0; n < 4; ++n) {
                #pragma unroll
                for (int r = 0; r < 4; ++r) {
                    float v = acc[m][n][r];
                    float u = __shfl_xor(v, 1, 64);     // partner col (U pre-act)
                    if (isV)
                        cs[r] += fast_tanh(v + bvv[n]) * fast_sigmoid(u + buu[n]) * www[n];
                }
            }
            #pragma unroll
            for (int r = 0; r < 4; ++r) {
                #pragma unroll
                for (int off = 1; off < 16; off <<= 1)
                    cs[r] += __shfl_xor(cs[r], off, 64);
            }
            if ((l & 15) == 0) {
                #pragma unroll
                for (int r = 0; r < 4; ++r)
                    partial[w][m * 16 + (l >> 4) * 4 + r] = cs[r];
            }
        }
    }
    __syncthreads();

    if (tid < BM) {
        int gi = i0 + tid;
        if (gi < N) {
            float s = partial[0][tid] + partial[1][tid] + partial[2][tid] + partial[3][tid] + bw[0];
            scores[(size_t)b * N + gi] = s;
            atten[(size_t)b * N + gi] = 0.0f;
        }
    }
}

// ---------------------------------------------------------------------------
// Kernel 2a: per (chunk, bag) local top-10 / bottom-10. 1 wave per block.
// cand layout: [b][r][0..9 top desc, 10..19 bottom asc]
// ---------------------------------------------------------------------------
__global__ __launch_bounds__(64) void select1_kernel(
    const float* __restrict__ scores, float* __restrict__ cv, int* __restrict__ ci,
    int N, int CH)
{
    const int r = blockIdx.x, b = blockIdx.y;
    const int tid = threadIdx.x;
    const float* s = scores + (size_t)b * N;
    const int start = r * CH;
    const int end = min(N, start + CH);

    float tv[KSEL]; int ti[KSEL];
    float lv[KSEL]; int li[KSEL];
    #pragma unroll
    for (int j = 0; j < KSEL; ++j) { tv[j] = -FLT_MAX; ti[j] = -1; lv[j] = FLT_MAX; li[j] = -1; }

    for (int i = start + tid; i < end; i += 64) {
        float v = s[i];
        if (v > tv[KSEL-1]) {
            #pragma unroll
            for (int j = KSEL-1; j >= 1; --j) {
                if (v > tv[j-1])      { tv[j] = tv[j-1]; ti[j] = ti[j-1]; }
                else if (v > tv[j])   { tv[j] = v;       ti[j] = i;       }
            }
            if (v > tv[0]) { tv[0] = v; ti[0] = i; }
        }
        if (v < lv[KSEL-1]) {
            #pragma unroll
            for (int j = KSEL-1; j >= 1; --j) {
                if (v < lv[j-1])      { lv[j] = lv[j-1]; li[j] = li[j-1]; }
                else if (v < lv[j])   { lv[j] = v;       li[j] = i;       }
            }
            if (v < lv[0]) { lv[0] = v; li[0] = i; }
        }
    }

    size_t base = ((size_t)b * NSEL1 + r) * 2 * KSEL;
    for (int rd = 0; rd < KSEL; ++rd) {
        float v = tv[0]; int who = tid;
        #pragma unroll
        for (int off = 32; off > 0; off >>= 1) {
            float ov = __shfl_down(v, off, 64);
            int ow = __shfl_down(who, off, 64);
            if (ov > v) { v = ov; who = ow; }
        }
        int bwho = __shfl(who, 0, 64);
        if (tid == bwho) {
            cv[base + rd] = tv[0]; ci[base + rd] = ti[0];
            #pragma unroll
            for (int j = 0; j < KSEL-1; ++j) { tv[j] = tv[j+1]; ti[j] = ti[j+1]; }
            tv[KSEL-1] = -FLT_MAX;
        }
    }
    for (int rd = 0; rd < KSEL; ++rd) {
        float v = lv[0]; int who = tid;
        #pragma unroll
        for (int off = 32; off > 0; off >>= 1) {
            float ov = __shfl_down(v, off, 64);
            int ow = __shfl_down(who, off, 64);
            if (ov < v) { v = ov; who = ow; }
        }
        int bwho = __shfl(who, 0, 64);
        if (tid == bwho) {
            cv[base + KSEL + rd] = lv[0]; ci[base + KSEL + rd] = li[0];
            #pragma unroll
            for (int j = 0; j < KSEL-1; ++j) { lv[j] = lv[j+1]; li[j] = li[j+1]; }
            lv[KSEL-1] = FLT_MAX;
        }
    }
}

// ---------------------------------------------------------------------------
// Kernel 2b (fused with Z): per bag merge candidates, softmax, scatter atten,
// then weighted gather Z[b,:] with all 256 threads.
// ---------------------------------------------------------------------------
__global__ __launch_bounds__(256) void select2_z_kernel(
    const float* __restrict__ cv, const int* __restrict__ ci,
    const float* __restrict__ x,
    float* __restrict__ atten, float* __restrict__ Z, int N)
{
    const int b = blockIdx.x;
    const int tid = threadIdx.x;
    __shared__ float selv[2*KSEL]; __shared__ int seli[2*KSEL];
    __shared__ float selw[2*KSEL];

    if (tid < 64) {
        float tv[KSEL]; int ti[KSEL];
        float lv[KSEL]; int li[KSEL];
        #pragma unroll
        for (int j = 0; j < KSEL; ++j) { tv[j] = -FLT_MAX; ti[j] = -1; lv[j] = FLT_MAX; li[j] = -1; }

        for (int c = tid; c < NSEL1 * KSEL; c += 64) {
            int rr = c / KSEL, jj = c % KSEL;
            size_t base = ((size_t)b * NSEL1 + rr) * 2 * KSEL;
            {
                float v = cv[base + jj]; int idx = ci[base + jj];
                if (v > tv[KSEL-1]) {
                    #pragma unroll
                    for (int j = KSEL-1; j >= 1; --j) {
                        if (v > tv[j-1])      { tv[j] = tv[j-1]; ti[j] = ti[j-1]; }
                        else if (v > tv[j])   { tv[j] = v;       ti[j] = idx;     }
                    }
                    if (v > tv[0]) { tv[0] = v; ti[0] = idx; }
                }
            }
            {
                float v = cv[base + KSEL + jj]; int idx = ci[base + KSEL + jj];
                if (v < lv[KSEL-1]) {
                    #pragma unroll
                    for (int j = KSEL-1; j >= 1; --j) {
                        if (v < lv[j-1])      { lv[j] = lv[j-1]; li[j] = li[j-1]; }
                        else if (v < lv[j])   { lv[j] = v;       li[j] = idx;     }
                    }
                    if (v < lv[0]) { lv[0] = v; li[0] = idx; }
                }
            }
        }

        for (int rd = 0; rd < KSEL; ++rd) {
            float v = tv[0]; int who = tid;
            #pragma unroll
            for (int off = 32; off > 0; off >>= 1) {
                float ov = __shfl_down(v, off, 64);
                int ow = __shfl_down(who, off, 64);
                if (ov > v) { v = ov; who = ow; }
            }
            int bwho = __shfl(who, 0, 64);
            if (tid == bwho) {
                selv[rd] = tv[0]; seli[rd] = ti[0];
                #pragma unroll
                for (int j = 0; j < KSEL-1; ++j) { tv[j] = tv[j+1]; ti[j] = ti[j+1]; }
                tv[KSEL-1] = -FLT_MAX;
            }
        }
        for (int rd = 0; rd < KSEL; ++rd) {
            float v = lv[0]; int who = tid;
            #pragma unroll
            for (int off = 32; off > 0; off >>= 1) {
                float ov = __shfl_down(v, off, 64);
                int ow = __shfl_down(who, off, 64);
                if (ov < v) { v = ov; who = ow; }
            }
            int bwho = __shfl(who, 0, 64);
            if (tid == bwho) {
                selv[KSEL + rd] = lv[0]; seli[KSEL + rd] = li[0];
                #pragma unroll
                for (int j = 0; j < KSEL-1; ++j) { lv[j] = lv[j+1]; li[j] = li[j+1]; }
                lv[KSEL-1] = FLT_MAX;
            }
        }
    }
    __syncthreads();

    if (tid == 0) {
        float m = -FLT_MAX;
        #pragma unroll
        for (int j = 0; j < 2*KSEL; ++j) m = fmaxf(m, selv[j]);
        float e[2*KSEL]; float sum = 0.f;
        #pragma unroll
        for (int j = 0; j < 2*KSEL; ++j) { e[j] = expf(selv[j] - m); sum += e[j]; }
        float inv = 1.0f / sum;
        #pragma unroll
        for (int j = 0; j < 2*KSEL; ++j) {
            float w = e[j] * inv;
            selw[j] = w;
            atten[(size_t)b * N + seli[j]] = w;
        }
    }
    __syncthreads();

    // Z gather: 256 threads x float4 = 1024 floats
    float4 acc = make_float4(0.f, 0.f, 0.f, 0.f);
    #pragma unroll
    for (int j = 0; j < 2*KSEL; ++j) {
        int idx = seli[j];
        float w = selw[j];
        const float4* xr = (const float4*)(x + ((size_t)b * N + idx) * INPUT_DIM);
        float4 v = xr[tid];
        acc.x = fmaf(w, v.x, acc.x);
        acc.y = fmaf(w, v.y, acc.y);
        acc.z = fmaf(w, v.z, acc.z);
        acc.w = fmaf(w, v.w, acc.w);
    }
    ((float4*)(Z + (size_t)b * INPUT_DIM))[tid] = acc;
}

extern "C" void kernel_launch(void* const* d_in, const int* in_sizes, int n_in,
                              void* d_out, int out_size, void* d_ws, size_t ws_size,
                              hipStream_t stream)
{
    const float* x  = (const float*)d_in[0];
    const float* Wv = (const float*)d_in[1];
    const float* bv = (const float*)d_in[2];
    const float* Wu = (const float*)d_in[3];
    const float* bu = (const float*)d_in[4];
    const float* Ww = (const float*)d_in[5];
    const float* bw = (const float*)d_in[6];

    const int B = 8;
    const int N = in_sizes[0] / (B * INPUT_DIM);   // 50000

    float* Z = (float*)d_out;                              // [B,1024]
    float* atten = (float*)d_out + (size_t)B * INPUT_DIM;  // [B,N]

    // workspace layout
    char* p = (char*)d_ws;
    float* scores = (float*)p;                  p += (size_t)B * N * sizeof(float);
    unsigned short* wp_hi = (unsigned short*)p; p += (size_t)INPUT_DIM * 256 * sizeof(unsigned short);
    unsigned short* wp_lo = (unsigned short*)p; p += (size_t)INPUT_DIM * 256 * sizeof(unsigned short);
    float* cand_v = (float*)p;                  p += (size_t)B * NSEL1 * 2 * KSEL * sizeof(float);
    int* cand_i = (int*)p;                      p += (size_t)B * NSEL1 * 2 * KSEL * sizeof(int);

    repack_kernel<<<512, 64, 0, stream>>>(Wv, Wu, wp_hi, wp_lo);

    dim3 g1((N + BM - 1) / BM, B);
    scores_kernel<<<g1, STH, 0, stream>>>(x, wp_hi, wp_lo, bv, bu, Ww, bw, scores, atten, N);

    int CH = (N + NSEL1 - 1) / NSEL1;
    dim3 g2(NSEL1, B);
    select1_kernel<<<g2, 64, 0, stream>>>(scores, cand_v, cand_i, N, CH);
    select2_z_kernel<<<B, 256, 0, stream>>>(cand_v, cand_i, x, atten, Z, N);
}

// Round 9
// 788.510 us; speedup vs baseline: 1.3992x; 1.3992x over previous
//
#include <hip/hip_runtime.h>
#include <math.h>
#include <float.h>

#define INPUT_DIM 1024
#define HIDDEN 128
#define KSEL 10

// scores kernel geometry: 4 waves, block tile 64 rows x 256 packed cols
#define BM 64
#define BK 64
#define KT (INPUT_DIM / BK)   // 16
#define STH 256
#define NSEL1 32              // stage-1 chunks per bag

typedef short short8 __attribute__((ext_vector_type(8)));
typedef float f32x4 __attribute__((ext_vector_type(4)));

static __device__ __forceinline__ unsigned short f2bf(float f) {
    union { float f; unsigned u; } v; v.f = f;
    unsigned r = v.u + 0x7FFF + ((v.u >> 16) & 1);   // RNE
    return (unsigned short)(r >> 16);
}
static __device__ __forceinline__ float bf2f(unsigned short h) {
    union { unsigned u; float f; } v; v.u = ((unsigned)h) << 16;
    return v.f;
}
// split (a,b) -> packed hi word (truncation) + packed lo word (RNE of residual)
static __device__ __forceinline__ void split2(float a, float b, unsigned& hw, unsigned& lw) {
    unsigned ua = __float_as_uint(a) & 0xFFFF0000u;
    unsigned ub = __float_as_uint(b) & 0xFFFF0000u;
    float ra = a - __uint_as_float(ua);
    float rb = b - __uint_as_float(ub);
    asm("v_perm_b32 %0, %1, %2, %3" : "=v"(hw) : "v"(ub), "v"(ua), "s"(0x07060302));
    asm("v_cvt_pk_bf16_f32 %0, %1, %2" : "=v"(lw) : "v"(ra), "v"(rb));
}
static __device__ __forceinline__ float fast_tanh(float a) {
    float e = __expf(2.0f * a);
    return 1.0f - 2.0f / (e + 1.0f);
}
static __device__ __forceinline__ float fast_sigmoid(float a) {
    return 1.0f / (1.0f + __expf(-a));
}

// ---------------------------------------------------------------------------
// Repack W into MFMA B-fragment order, split into bf16 hi/lo (RNE both).
// pc = 2h + (0 Wv, 1 Wu). wp[kg][cg][lane][e]: k = kg*32+(lane>>4)*8+e,
// pc = cg*16+(lane&15). grid 512 x 64.
// ---------------------------------------------------------------------------
__global__ __launch_bounds__(64) void repack_kernel(
    const float* __restrict__ Wv, const float* __restrict__ Wu,
    unsigned short* __restrict__ wp_hi, unsigned short* __restrict__ wp_lo)
{
    int bid = blockIdx.x;           // kg*16 + cg
    int l = threadIdx.x;
    int pc = (bid & 15) * 16 + (l & 15);
    int h = pc >> 1;
    const float* src = (pc & 1) ? Wu : Wv;
    int kbase = (bid >> 4) * 32 + (l >> 4) * 8;
    size_t off = ((size_t)bid * 64 + l) * 8;
    #pragma unroll
    for (int e = 0; e < 8; ++e) {
        float w = src[(size_t)(kbase + e) * HIDDEN + h];
        unsigned short hi = f2bf(w);
        unsigned short lo = f2bf(w - bf2f(hi));
        wp_hi[off + e] = hi;
        wp_lo[off + e] = lo;
    }
}

// ---------------------------------------------------------------------------
// Kernel 1: fused scores via split-bf16 3-term MFMA.
// 4 waves self-stage raw fp32 x via global_load_lds into a 3-buffer rotation,
// DMA issued 2 tiles ahead, MID-phase (between the ks0 and ks1 MFMA blocks).
// vmcnt is an in-order FIFO: a B-frag wait drains every older DMA, so the
// DMA is placed where its forced drain has had >=1 MFMA-block of flight:
//   [bar] issue B(kt,1) | MFMA ks0 (B(kt,0) already in regs, no wait)
//   | STAGE(kt+2) | MFMA ks1 (B(kt,1) wait drains DMA ~free)
//   | issue B(kt+1,0) | raw s_barrier (loads stay in flight across it)
// B-frags are software-pipelined one ks ahead so every wait is counted-clean.
// ---------------------------------------------------------------------------
__global__ __launch_bounds__(STH) void scores_kernel(
    const float* __restrict__ x,
    const unsigned short* __restrict__ wp_hi, const unsigned short* __restrict__ wp_lo,
    const float* __restrict__ bv, const float* __restrict__ bu,
    const float* __restrict__ Ww, const float* __restrict__ bw,
    float* __restrict__ scores, float* __restrict__ atten, int N)
{
    __shared__ __align__(16) float buf[3][BM * BK];   // 48 KB (3 x 16 KB)
    __shared__ float partial[4][BM];                  // 1 KB

    const int tid = threadIdx.x;
    const int l = tid & 63;
    const int w = tid >> 6;        // wave id 0..3 (also wave-col group)
    const int b = blockIdx.y;
    const int i0 = blockIdx.x * BM;
    const float* xb = x + (size_t)b * N * INPUT_DIM;

    // Per-lane pre-swizzled global source pointers; wave w stages rows
    // [w*16, w*16+16). LDS[row][c] holds global chunk (c ^ (row&7)).
    const float* gp[4];
    #pragma unroll
    for (int j = 0; j < 4; ++j) {
        int lr = w * 16 + j * 4 + (l >> 4);          // local row
        int gi = min(i0 + lr, N - 1);                // clamp tail rows
        int csw = (l & 15) ^ (lr & 7);               // source chunk (involution)
        gp[j] = xb + (size_t)gi * INPUT_DIM + csw * 4;
    }

    f32x4 acc[4][4];
    #pragma unroll
    for (int m = 0; m < 4; ++m)
        #pragma unroll
        for (int n = 0; n < 4; ++n)
            acc[m][n] = (f32x4){0.f, 0.f, 0.f, 0.f};

#define STAGE(T) do { \
        float* _dst = &buf[(T) % 3][0]; \
        _Pragma("unroll") \
        for (int j = 0; j < 4; ++j) { \
            __builtin_amdgcn_global_load_lds( \
                (const __attribute__((address_space(1))) void*)gp[j], \
                (__attribute__((address_space(3))) void*)(_dst + (w * 16 + j * 4) * BK), \
                16, 0, 0); \
            gp[j] += BK; \
        } \
    } while (0)

#define LOAD_B(BH, BL, KG) do { \
        _Pragma("unroll") \
        for (int n = 0; n < 4; ++n) { \
            unsigned boff = (unsigned)((((KG) * 16 + w * 4 + n) * 64 + l) * 8); \
            BH[n] = *(const short8*)(wp_hi + boff); \
            BL[n] = *(const short8*)(wp_lo + boff); \
        } \
    } while (0)

#define MFMA_KS(BUF, KS, BH, BL) do { \
        __builtin_amdgcn_s_setprio(1); \
        _Pragma("unroll") \
        for (int m = 0; m < 4; ++m) { \
            int row = m * 16 + (l & 15); \
            int k4a = (KS) * 8 + (l >> 4) * 2; \
            int sw = l & 7;                      /* row&7 == l&7 here */ \
            f32x4 c0 = *(const f32x4*)(&BUF[row * BK + ((k4a)     ^ sw) * 4]); \
            f32x4 c1 = *(const f32x4*)(&BUF[row * BK + ((k4a + 1) ^ sw) * 4]); \
            union { short8 s; uint4 u; } Ah, Al; \
            split2(c0[0], c0[1], Ah.u.x, Al.u.x); \
            split2(c0[2], c0[3], Ah.u.y, Al.u.y); \
            split2(c1[0], c1[1], Ah.u.z, Al.u.z); \
            split2(c1[2], c1[3], Ah.u.w, Al.u.w); \
            _Pragma("unroll") \
            for (int n = 0; n < 4; ++n) { \
                acc[m][n] = __builtin_amdgcn_mfma_f32_16x16x32_bf16(Ah.s, BH[n], acc[m][n], 0, 0, 0); \
                acc[m][n] = __builtin_amdgcn_mfma_f32_16x16x32_bf16(Al.s, BH[n], acc[m][n], 0, 0, 0); \
                acc[m][n] = __builtin_amdgcn_mfma_f32_16x16x32_bf16(Ah.s, BL[n], acc[m][n], 0, 0, 0); \
            } \
        } \
        __builtin_amdgcn_s_setprio(0); \
    } while (0)

    short8 bh0[4], bl0[4], bh1[4], bl1[4];

    // prologue: B(0,0) first (oldest in FIFO), then DMA tiles 0 and 1.
    LOAD_B(bh0, bl0, 0);
    STAGE(0);
    STAGE(1);
    // drain B(0,0) + tile-0 DMA; tile-1 DMA (4 ops) stays in flight.
    asm volatile("s_waitcnt vmcnt(4)" ::: "memory");
    __builtin_amdgcn_s_barrier();

    for (int kt = 0; kt < KT; ++kt) {
        const float* BUF = &buf[kt % 3][0];
        LOAD_B(bh1, bl1, kt * 2 + 1);             // B(kt,ks1) in flight
        MFMA_KS(BUF, 0, bh0, bl0);                // uses regs, no vmcnt wait
        if (kt + 2 < KT) STAGE(kt + 2);           // DMA drained by ks1's B-wait
        __builtin_amdgcn_sched_barrier(0);        // pin: don't sink the DMA
        MFMA_KS(BUF, 1, bh1, bl1);                // wait drains DMA after ks0 flight
        if (kt + 1 < KT) LOAD_B(bh0, bl0, kt * 2 + 2);   // B(kt+1,ks0)
        __builtin_amdgcn_s_barrier();             // raw: loads fly across
    }

#undef STAGE
#undef LOAD_B
#undef MFMA_KS

    // ---- epilogue: gate, project, row-reduce ----
    float bvv[4], buu[4], www[4];
    #pragma unroll
    for (int n = 0; n < 4; ++n) {
        int h = (w * 64 + n * 16 + (l & 15)) >> 1;
        bvv[n] = bv[h]; buu[n] = bu[h]; www[n] = Ww[h];
    }
    const bool isV = ((l & 1) == 0);

    #pragma unroll
    for (int m = 0; m < 4; ++m) {
        float cs[4] = {0.f, 0.f, 0.f, 0.f};
        #pragma unroll
        for (int n = 0; n < 4; ++n) {
            #pragma unroll
            for (int r = 0; r < 4; ++r) {
                float v = acc[m][n][r];
                float u = __shfl_xor(v, 1, 64);     // partner col (U pre-act)
                if (isV)
                    cs[r] += fast_tanh(v + bvv[n]) * fast_sigmoid(u + buu[n]) * www[n];
            }
        }
        #pragma unroll
        for (int r = 0; r < 4; ++r) {
            #pragma unroll
            for (int off = 1; off < 16; off <<= 1)
                cs[r] += __shfl_xor(cs[r], off, 64);
        }
        if ((l & 15) == 0) {
            #pragma unroll
            for (int r = 0; r < 4; ++r)
                partial[w][m * 16 + (l >> 4) * 4 + r] = cs[r];
        }
    }
    __syncthreads();

    if (tid < BM) {
        int gi = i0 + tid;
        if (gi < N) {
            float s = partial[0][tid] + partial[1][tid] + partial[2][tid] + partial[3][tid] + bw[0];
            scores[(size_t)b * N + gi] = s;
            atten[(size_t)b * N + gi] = 0.0f;
        }
    }
}

// ---------------------------------------------------------------------------
// Kernel 2a: per (chunk, bag) local top-10 / bottom-10. 1 wave per block.
// cand layout: [b][r][0..9 top desc, 10..19 bottom asc]
// ---------------------------------------------------------------------------
__global__ __launch_bounds__(64) void select1_kernel(
    const float* __restrict__ scores, float* __restrict__ cv, int* __restrict__ ci,
    int N, int CH)
{
    const int r = blockIdx.x, b = blockIdx.y;
    const int tid = threadIdx.x;
    const float* s = scores + (size_t)b * N;
    const int start = r * CH;
    const int end = min(N, start + CH);

    float tv[KSEL]; int ti[KSEL];
    float lv[KSEL]; int li[KSEL];
    #pragma unroll
    for (int j = 0; j < KSEL; ++j) { tv[j] = -FLT_MAX; ti[j] = -1; lv[j] = FLT_MAX; li[j] = -1; }

    for (int i = start + tid; i < end; i += 64) {
        float v = s[i];
        if (v > tv[KSEL-1]) {
            #pragma unroll
            for (int j = KSEL-1; j >= 1; --j) {
                if (v > tv[j-1])      { tv[j] = tv[j-1]; ti[j] = ti[j-1]; }
                else if (v > tv[j])   { tv[j] = v;       ti[j] = i;       }
            }
            if (v > tv[0]) { tv[0] = v; ti[0] = i; }
        }
        if (v < lv[KSEL-1]) {
            #pragma unroll
            for (int j = KSEL-1; j >= 1; --j) {
                if (v < lv[j-1])      { lv[j] = lv[j-1]; li[j] = li[j-1]; }
                else if (v < lv[j])   { lv[j] = v;       li[j] = i;       }
            }
            if (v < lv[0]) { lv[0] = v; li[0] = i; }
        }
    }

    size_t base = ((size_t)b * NSEL1 + r) * 2 * KSEL;
    for (int rd = 0; rd < KSEL; ++rd) {
        float v = tv[0]; int who = tid;
        #pragma unroll
        for (int off = 32; off > 0; off >>= 1) {
            float ov = __shfl_down(v, off, 64);
            int ow = __shfl_down(who, off, 64);
            if (ov > v) { v = ov; who = ow; }
        }
        int bwho = __shfl(who, 0, 64);
        if (tid == bwho) {
            cv[base + rd] = tv[0]; ci[base + rd] = ti[0];
            #pragma unroll
            for (int j = 0; j < KSEL-1; ++j) { tv[j] = tv[j+1]; ti[j] = ti[j+1]; }
            tv[KSEL-1] = -FLT_MAX;
        }
    }
    for (int rd = 0; rd < KSEL; ++rd) {
        float v = lv[0]; int who = tid;
        #pragma unroll
        for (int off = 32; off > 0; off >>= 1) {
            float ov = __shfl_down(v, off, 64);
            int ow = __shfl_down(who, off, 64);
            if (ov < v) { v = ov; who = ow; }
        }
        int bwho = __shfl(who, 0, 64);
        if (tid == bwho) {
            cv[base + KSEL + rd] = lv[0]; ci[base + KSEL + rd] = li[0];
            #pragma unroll
            for (int j = 0; j < KSEL-1; ++j) { lv[j] = lv[j+1]; li[j] = li[j+1]; }
            lv[KSEL-1] = FLT_MAX;
        }
    }
}

// ---------------------------------------------------------------------------
// Kernel 2b (fused with Z): per bag merge candidates, softmax, scatter atten,
// then weighted gather Z[b,:] with all 256 threads.
// ---------------------------------------------------------------------------
__global__ __launch_bounds__(256) void select2_z_kernel(
    const float* __restrict__ cv, const int* __restrict__ ci,
    const float* __restrict__ x,
    float* __restrict__ atten, float* __restrict__ Z, int N)
{
    const int b = blockIdx.x;
    const int tid = threadIdx.x;
    __shared__ float selv[2*KSEL]; __shared__ int seli[2*KSEL];
    __shared__ float selw[2*KSEL];

    if (tid < 64) {
        float tv[KSEL]; int ti[KSEL];
        float lv[KSEL]; int li[KSEL];
        #pragma unroll
        for (int j = 0; j < KSEL; ++j) { tv[j] = -FLT_MAX; ti[j] = -1; lv[j] = FLT_MAX; li[j] = -1; }

        for (int c = tid; c < NSEL1 * KSEL; c += 64) {
            int rr = c / KSEL, jj = c % KSEL;
            size_t base = ((size_t)b * NSEL1 + rr) * 2 * KSEL;
            {
                float v = cv[base + jj]; int idx = ci[base + jj];
                if (v > tv[KSEL-1]) {
                    #pragma unroll
                    for (int j = KSEL-1; j >= 1; --j) {
                        if (v > tv[j-1])      { tv[j] = tv[j-1]; ti[j] = ti[j-1]; }
                        else if (v > tv[j])   { tv[j] = v;       ti[j] = idx;     }
                    }
                    if (v > tv[0]) { tv[0] = v; ti[0] = idx; }
                }
            }
            {
                float v = cv[base + KSEL + jj]; int idx = ci[base + KSEL + jj];
                if (v < lv[KSEL-1]) {
                    #pragma unroll
                    for (int j = KSEL-1; j >= 1; --j) {
                        if (v < lv[j-1])      { lv[j] = lv[j-1]; li[j] = li[j-1]; }
                        else if (v < lv[j])   { lv[j] = v;       li[j] = idx;     }
                    }
                    if (v < lv[0]) { lv[0] = v; li[0] = idx; }
                }
            }
        }

        for (int rd = 0; rd < KSEL; ++rd) {
            float v = tv[0]; int who = tid;
            #pragma unroll
            for (int off = 32; off > 0; off >>= 1) {
                float ov = __shfl_down(v, off, 64);
                int ow = __shfl_down(who, off, 64);
                if (ov > v) { v = ov; who = ow; }
            }
            int bwho = __shfl(who, 0, 64);
            if (tid == bwho) {
                selv[rd] = tv[0]; seli[rd] = ti[0];
                #pragma unroll
                for (int j = 0; j < KSEL-1; ++j) { tv[j] = tv[j+1]; ti[j] = ti[j+1]; }
                tv[KSEL-1] = -FLT_MAX;
            }
        }
        for (int rd = 0; rd < KSEL; ++rd) {
            float v = lv[0]; int who = tid;
            #pragma unroll
            for (int off = 32; off > 0; off >>= 1) {
                float ov = __shfl_down(v, off, 64);
                int ow = __shfl_down(who, off, 64);
                if (ov < v) { v = ov; who = ow; }
            }
            int bwho = __shfl(who, 0, 64);
            if (tid == bwho) {
                selv[KSEL + rd] = lv[0]; seli[KSEL + rd] = li[0];
                #pragma unroll
                for (int j = 0; j < KSEL-1; ++j) { lv[j] = lv[j+1]; li[j] = li[j+1]; }
                lv[KSEL-1] = FLT_MAX;
            }
        }
    }
    __syncthreads();

    if (tid == 0) {
        float m = -FLT_MAX;
        #pragma unroll
        for (int j = 0; j < 2*KSEL; ++j) m = fmaxf(m, selv[j]);
        float e[2*KSEL]; float sum = 0.f;
        #pragma unroll
        for (int j = 0; j < 2*KSEL; ++j) { e[j] = expf(selv[j] - m); sum += e[j]; }
        float inv = 1.0f / sum;
        #pragma unroll
        for (int j = 0; j < 2*KSEL; ++j) {
            float w = e[j] * inv;
            selw[j] = w;
            atten[(size_t)b * N + seli[j]] = w;
        }
    }
    __syncthreads();

    // Z gather: 256 threads x float4 = 1024 floats
    float4 acc = make_float4(0.f, 0.f, 0.f, 0.f);
    #pragma unroll
    for (int j = 0; j < 2*KSEL; ++j) {
        int idx = seli[j];
        float w = selw[j];
        const float4* xr = (const float4*)(x + ((size_t)b * N + idx) * INPUT_DIM);
        float4 v = xr[tid];
        acc.x = fmaf(w, v.x, acc.x);
        acc.y = fmaf(w, v.y, acc.y);
        acc.z = fmaf(w, v.z, acc.z);
        acc.w = fmaf(w, v.w, acc.w);
    }
    ((float4*)(Z + (size_t)b * INPUT_DIM))[tid] = acc;
}

extern "C" void kernel_launch(void* const* d_in, const int* in_sizes, int n_in,
                              void* d_out, int out_size, void* d_ws, size_t ws_size,
                              hipStream_t stream)
{
    const float* x  = (const float*)d_in[0];
    const float* Wv = (const float*)d_in[1];
    const float* bv = (const float*)d_in[2];
    const float* Wu = (const float*)d_in[3];
    const float* bu = (const float*)d_in[4];
    const float* Ww = (const float*)d_in[5];
    const float* bw = (const float*)d_in[6];

    const int B = 8;
    const int N = in_sizes[0] / (B * INPUT_DIM);   // 50000

    float* Z = (float*)d_out;                              // [B,1024]
    float* atten = (float*)d_out + (size_t)B * INPUT_DIM;  // [B,N]

    // workspace layout
    char* p = (char*)d_ws;
    float* scores = (float*)p;                  p += (size_t)B * N * sizeof(float);
    unsigned short* wp_hi = (unsigned short*)p; p += (size_t)INPUT_DIM * 256 * sizeof(unsigned short);
    unsigned short* wp_lo = (unsigned short*)p; p += (size_t)INPUT_DIM * 256 * sizeof(unsigned short);
    float* cand_v = (float*)p;                  p += (size_t)B * NSEL1 * 2 * KSEL * sizeof(float);
    int* cand_i = (int*)p;                      p += (size_t)B * NSEL1 * 2 * KSEL * sizeof(int);

    repack_kernel<<<512, 64, 0, stream>>>(Wv, Wu, wp_hi, wp_lo);

    dim3 g1((N + BM - 1) / BM, B);
    scores_kernel<<<g1, STH, 0, stream>>>(x, wp_hi, wp_lo, bv, bu, Ww, bw, scores, atten, N);

    int CH = (N + NSEL1 - 1) / NSEL1;
    dim3 g2(NSEL1, B);
    select1_kernel<<<g2, 64, 0, stream>>>(scores, cand_v, cand_i, N, CH);
    select2_z_kernel<<<B, 256, 0, stream>>>(cand_v, cand_i, x, atten, Z, N);
}